// Round 6
// baseline (931.602 us; speedup 1.0000x reference)
//
#include <hip/hip_runtime.h>
#include <math.h>

#define N_NODES 50000
#define E_EDGES 800000
#define HID 256
#define EPS_BN 1e-5f

// aggregate: blocks per channel-slice (8 slices, slice = blockIdx & 7 -> XCD)
#define AGG_BPS 256

// parallel scan chunking
#define SCAN_CHUNK 1024
#define SCAN_NCH ((N_NODES + SCAN_CHUNK - 1) / SCAN_CHUNK)   // 49

typedef __attribute__((ext_vector_type(8))) short short8;            // bf16x8 MFMA frag
typedef __attribute__((ext_vector_type(4))) float floatx4;           // fp32x4 acc frag
typedef __attribute__((ext_vector_type(8))) unsigned short ushort8v; // bf16x8 mem

// ---------------------------------------------------------------------------
// bf16 helpers (RNE)
// ---------------------------------------------------------------------------
__device__ __forceinline__ unsigned short f2bf(float f) {
    unsigned u = __float_as_uint(f);
    u = (u + 0x7FFFu + ((u >> 16) & 1u)) >> 16;
    return (unsigned short)u;
}
__device__ __forceinline__ float bf2f(unsigned short b) {
    return __uint_as_float(((unsigned)b) << 16);
}
// BN scale/shift from raw stats (sum, sumsq) + gamma/beta
__device__ __forceinline__ void bn_scsh(const float* stats, const float* gamma,
                                        const float* beta, int ch,
                                        float& sc, float& sh) {
    const float invn = 1.0f / (float)N_NODES;
    float mean = stats[ch] * invn;
    float var = stats[HID + ch] * invn - mean * mean;
    var = fmaxf(var, 0.f);
    sc = gamma[ch] * rsqrtf(var + EPS_BN);
    sh = beta[ch] - mean * sc;
}

// ---------------------------------------------------------------------------
// Graph preprocessing
// ---------------------------------------------------------------------------
__global__ __launch_bounds__(256) void k_deg(const int* __restrict__ rows,
                                             int* __restrict__ deg) {
    int e = blockIdx.x * 256 + threadIdx.x;   // E_EDGES % 256 == 0
    atomicAdd(&deg[rows[e]], 1);
}

__global__ __launch_bounds__(256) void k_dinv(const int* __restrict__ deg,
                                              float* __restrict__ dinv) {
    int n = blockIdx.x * 256 + threadIdx.x;
    if (n < N_NODES) dinv[n] = rsqrtf((float)deg[n] + 1.0f);  // +1 self loop
}

// parallel exclusive scan, 3 kernels
__global__ __launch_bounds__(1024) void k_scan1(const int* __restrict__ deg,
                                                int* __restrict__ rowptr,
                                                int* __restrict__ bsum) {
    __shared__ int wsum[16];
    int tid = threadIdx.x, lane = tid & 63, w = tid >> 6;
    int idx = blockIdx.x * SCAN_CHUNK + tid;
    int v = (idx < N_NODES) ? deg[idx] : 0;
    int x = v;
#pragma unroll
    for (int d = 1; d < 64; d <<= 1) {
        int t = __shfl_up(x, d);
        if (lane >= d) x += t;
    }
    if (lane == 63) wsum[w] = x;
    __syncthreads();
    if (w == 0) {
        int ws = (lane < 16) ? wsum[lane] : 0;
#pragma unroll
        for (int d = 1; d < 16; d <<= 1) {
            int t = __shfl_up(ws, d);
            if (lane >= d) ws += t;
        }
        if (lane < 16) wsum[lane] = ws;  // inclusive over waves
    }
    __syncthreads();
    int wbase = (w > 0) ? wsum[w - 1] : 0;
    if (idx < N_NODES) rowptr[idx] = wbase + x - v;   // block-local exclusive
    if (tid == 0) bsum[blockIdx.x] = wsum[15];        // block total
}
__global__ __launch_bounds__(64) void k_scan2(const int* __restrict__ bsum,
                                              int* __restrict__ boff) {
    int lane = threadIdx.x;
    int v = (lane < SCAN_NCH) ? bsum[lane] : 0;
    int x = v;
#pragma unroll
    for (int d = 1; d < 64; d <<= 1) {
        int t = __shfl_up(x, d);
        if (lane >= d) x += t;
    }
    if (lane < SCAN_NCH) boff[lane] = x - v;
    if (lane == SCAN_NCH - 1) boff[SCAN_NCH] = x;     // grand total
}
__global__ __launch_bounds__(1024) void k_scan3(int* __restrict__ rowptr,
                                                const int* __restrict__ boff) {
    int idx = blockIdx.x * SCAN_CHUNK + threadIdx.x;
    if (idx < N_NODES) rowptr[idx] += boff[blockIdx.x];
    if (blockIdx.x == 0 && threadIdx.x == 0) rowptr[N_NODES] = boff[SCAN_NCH];
}

__global__ __launch_bounds__(256) void k_fill(const int* __restrict__ rows,
                                              const int* __restrict__ cols,
                                              const int* __restrict__ rowptr,
                                              int* __restrict__ cursor,
                                              int* __restrict__ colidx) {
    int e = blockIdx.x * 256 + threadIdx.x;
    int r = rows[e];
    int pos = atomicAdd(&cursor[r], 1);
    colidx[rowptr[r] + pos] = cols[e];
}

// ---------------------------------------------------------------------------
// fp32 [N][512] -> bf16 slice-major [16][N][32]
// ---------------------------------------------------------------------------
__global__ __launch_bounds__(256) void k_f2bf_slice(const float* __restrict__ X,
                                                    unsigned short* __restrict__ Y) {
    int i = blockIdx.x * 256 + threadIdx.x;     // over 16*N*4 ushort8 groups, exact
    int slice = i / (N_NODES * 4);              // 0..15
    int rem = i - slice * (N_NODES * 4);
    int node = rem >> 2, p8 = rem & 3;
    const float* xp = X + (size_t)node * 512 + slice * 32 + p8 * 8;
    float4 va = ((const float4*)xp)[0];
    float4 vb = ((const float4*)xp)[1];
    ushort8v o;
    o[0] = f2bf(va.x); o[1] = f2bf(va.y); o[2] = f2bf(va.z); o[3] = f2bf(va.w);
    o[4] = f2bf(vb.x); o[5] = f2bf(vb.y); o[6] = f2bf(vb.z); o[7] = f2bf(vb.w);
    *(ushort8v*)(Y + (size_t)i * 8) = o;
}

// batched W transpose: nmat matrices [K][256] fp32 -> [256][K] bf16 each
__global__ __launch_bounds__(256) void k_wt(const float* __restrict__ W,
                                            unsigned short* __restrict__ Wt,
                                            int K, int total) {
    int idx = blockIdx.x * 256 + threadIdx.x;
    if (idx >= total) return;
    int KS = K << 8;
    int m = idx / KS;
    int rel = idx - m * KS;
    int k = rel >> 8;          // / HID
    int n = rel & 255;         // % HID
    Wt[(size_t)m * KS + (size_t)n * K + k] = f2bf(W[idx]);
}

// ---------------------------------------------------------------------------
// bf16 MFMA GEMM: C(bf16) = rowscale(.)*(A @ Bt^T)
//   ROUND-10: 2-phase DOUBLE-BUFFERED k-loop (BK=32 chunks). The old
//   stage->barrier->compute structure exposed a full L3-load latency per
//   K-step (implicit vmcnt(0) at the barrier drained loads issued 0 cycles
//   earlier). Now: prologue stages chunk 0; each iter issues stage(c+1)
//   into the alternate 8KB buffers FIRST, then ds_read+MFMA on chunk c
//   (~200-350 cy) while the loads fly, then one __syncthreads(). Barrier
//   count per K unchanged vs the round-8 double-pump; latency exposure per
//   barrier drops from ~full to ~max(0, lat - compute).
//   LDS 36 KB (4x8KB staging union'd with 34.8KB epilogue tile + 1KB stats)
//   -> 4 blocks/CU preserved.
//   A: slice-major [K/32][N][32]; Bt: [256][K]; C slice-major [8][N][32].
//   Epilogue through LDS (round-9): pad-136 tile, 8x16B coalesced stores.
// ---------------------------------------------------------------------------
__global__ __launch_bounds__(256) void k_gemm_mfma(
    const unsigned short* __restrict__ A0,
    const unsigned short* __restrict__ A1, int K0, int K,
    const unsigned short* __restrict__ Bt,
    unsigned short* __restrict__ C,
    const float* __restrict__ rowscale,
    float* __restrict__ stats)
{
    __shared__ alignas(16) unsigned char smem[36864];
    // staging: A buffers at ushort-offset 0 / 4096, B at 8192 / 12288
    unsigned short* sbase = (unsigned short*)smem;
    int tid = threadIdx.x;
    int wid = tid >> 6, lane = tid & 63;
    int row0 = blockIdx.x * 128;
    int n0 = blockIdx.y * 128;
    int wrow = (wid & 1) * 64, wcol = (wid >> 1) * 64;
    int lr = lane >> 2;            // staging: row within 16-row group
    int lk = (lane & 3) * 8;       // staging: element offset in k
    int qq = lane >> 4, mr = lane & 15;

    floatx4 acc[4][4];
#pragma unroll
    for (int i = 0; i < 4; ++i)
#pragma unroll
        for (int j = 0; j < 4; ++j) {
            floatx4 z = {0.f, 0.f, 0.f, 0.f};
            acc[i][j] = z;
        }

    int KL = K >> 5;   // number of 32-K chunks (K0 % 32 == 0 guaranteed)

    auto stage = [&](int c, int b) {
        int kk = c << 5;
        const unsigned short* Abase =
            (kk < K0) ? A0 + (size_t)(kk >> 5) * (N_NODES * 32)
                      : A1 + (size_t)((kk - K0) >> 5) * (N_NODES * 32);
        unsigned short* Adst = sbase + b * 4096;
        unsigned short* Bdst = sbase + 8192 + b * 4096;
#pragma unroll
        for (int i = 0; i < 2; ++i) {
            int rloc = wid * 32 + i * 16 + lr;
            int grow = row0 + rloc;
            if (grow > N_NODES - 1) grow = N_NODES - 1;  // clamp (stores guarded)
            const unsigned short* gp = Abase + (size_t)grow * 32 + lk;
            unsigned short* l = Adst + (wid * 32 + i * 16) * 32;
            __builtin_amdgcn_global_load_lds(
                (const __attribute__((address_space(1))) void*)gp,
                (__attribute__((address_space(3))) void*)l, 16, 0, 0);
        }
#pragma unroll
        for (int i = 0; i < 2; ++i) {
            int nloc = wid * 32 + i * 16 + lr;
            const unsigned short* gp = Bt + (size_t)(n0 + nloc) * K + kk + lk;
            unsigned short* l = Bdst + (wid * 32 + i * 16) * 32;
            __builtin_amdgcn_global_load_lds(
                (const __attribute__((address_space(1))) void*)gp,
                (__attribute__((address_space(3))) void*)l, 16, 0, 0);
        }
    };

    stage(0, 0);
    __syncthreads();
    for (int c = 0; c < KL; ++c) {
        int cur = c & 1;
        if (c + 1 < KL) stage(c + 1, cur ^ 1);   // issue next chunk FIRST
        const unsigned short* Asrc = sbase + cur * 4096;
        const unsigned short* Bsrc = sbase + 8192 + cur * 4096;
        short8 af[4], bfv[4];
#pragma unroll
        for (int i = 0; i < 4; ++i)
            af[i] = *(const short8*)(Asrc + (wrow + i * 16 + mr) * 32 + qq * 8);
#pragma unroll
        for (int j = 0; j < 4; ++j)
            bfv[j] = *(const short8*)(Bsrc + (wcol + j * 16 + mr) * 32 + qq * 8);
#pragma unroll
        for (int i = 0; i < 4; ++i)
#pragma unroll
            for (int j = 0; j < 4; ++j)
                acc[i][j] = __builtin_amdgcn_mfma_f32_16x16x32_bf16(
                    af[i], bfv[j], acc[i][j], 0, 0, 0);
        __syncthreads();   // drains stage(c+1) loads (issued ~full compute ago)
    }

    // ---- epilogue through LDS ----
    unsigned short* lds_c = (unsigned short*)smem;        // [128][136] ushort
    float* ls = (float*)(smem + 34816);                   // [128] col sums
    float* lq = ls + 128;                                 // [128] col sumsq
    if (stats) ((float*)(smem + 34816))[tid] = 0.f;       // zero ls+lq

    float psum[4] = {0.f, 0.f, 0.f, 0.f};
    float psq[4]  = {0.f, 0.f, 0.f, 0.f};
#pragma unroll
    for (int i = 0; i < 4; ++i) {
        int trow_base = wrow + i * 16 + qq * 4;
#pragma unroll
        for (int r = 0; r < 4; ++r) {
            int trow = trow_base + r;
            int grow = row0 + trow;
            bool rok = grow < N_NODES;
            float rs = 1.0f;
            if (rowscale && rok) rs = rowscale[grow];
#pragma unroll
            for (int j = 0; j < 4; ++j) {
                float v = acc[i][j][r] * rs;
                lds_c[trow * 136 + wcol + j * 16 + mr] = f2bf(v);
                if (rok) { psum[j] += v; psq[j] += v * v; }
            }
        }
    }
    __syncthreads();
    if (stats) {
#pragma unroll
        for (int j = 0; j < 4; ++j) {
            int lc = wcol + j * 16 + mr;
            atomicAdd(&ls[lc], psum[j]);
            atomicAdd(&lq[lc], psq[j]);
        }
    }
    // coalesced slice-major stores: 8 x 16B per thread
    int rowlim = N_NODES - row0; if (rowlim > 128) rowlim = 128;
    int sbase_n = n0 >> 5;
#pragma unroll
    for (int u = 0; u < 8; ++u) {
        int uid = tid + 256 * u;            // 0..2047
        int row = uid >> 4;
        int q = (uid >> 2) & 3;
        int sub = uid & 3;
        if (row < rowlim) {
            ushort8v vv = *(const ushort8v*)(lds_c + row * 136 + q * 32 + sub * 8);
            *(ushort8v*)(C + ((size_t)(sbase_n + q) * N_NODES + row0 + row) * 32 + sub * 8) = vv;
        }
    }
    if (stats) {
        __syncthreads();
        if (tid < 128) atomicAdd(&stats[n0 + tid], ls[tid]);
        else atomicAdd(&stats[HID + n0 + (tid - 128)], lq[tid - 128]);
    }
}

// ---------------------------------------------------------------------------
// GCN aggregation (round-7 version, known-good 64.5 us / 32.2 MB FETCH):
// channel-sliced (slice = blockIdx&7 -> XCD; [N][32] bf16 = 3.2 MB < 4 MB
// per-XCD L2) + group-per-node (8-lane group owns a node, ushort4/lane)
// + 2-stage software pipeline.
// ---------------------------------------------------------------------------
__global__ __launch_bounds__(256) void k_aggregate_bf(
    const unsigned short* __restrict__ g,   // [8][N][32] bf16
    unsigned short* __restrict__ outp,      // [8][N][32] bf16
    const int* __restrict__ rowptr,
    const int* __restrict__ colidx,
    const float* __restrict__ dinv,
    float* __restrict__ stats) {
    int lane = threadIdx.x & 63;
    int wid = threadIdx.x >> 6;
    int slice = blockIdx.x & 7;
    int bslice = blockIdx.x >> 3;
    const unsigned short* gs = g + (size_t)slice * (N_NODES * 32);
    unsigned short* os = outp + (size_t)slice * (N_NODES * 32);
    int g8 = lane >> 3;   // group 0..7 (owns one node per round)
    int l8 = lane & 7;    // lane within group: channels l8*4 .. l8*4+3
    int wavebase = (bslice * 4 + wid) * 8;
    const int stride = AGG_BPS * 4 * 8;   // nodes per round (8192)

    float sa0 = 0.f, sa1 = 0.f, sa2 = 0.f, sa3 = 0.f;  // per-lane stats acc
    float qa0 = 0.f, qa1 = 0.f, qa2 = 0.f, qa3 = 0.f;

    for (int nb = wavebase; nb < N_NODES; nb += stride) {
        int node = nb + g8;
        bool valid = node < N_NODES;
        int nc = valid ? node : N_NODES - 1;
        int s = rowptr[nc];
        int e = valid ? rowptr[nc + 1] : s;
        int e1 = e - 1;
        // index clamp: keeps prefetch loads in-bounds for any j >= s
        auto cl = [&](int j) { int t = j < e1 ? j : e1; return t > 0 ? t : 0; };

        // init accumulators with the self contribution (overlaps edge loop)
        ushort4 sv = *(const ushort4*)(gs + ((size_t)nc << 5) + (l8 << 2));
        float rs = dinv[nc];
        float a0 = bf2f(sv.x), a1 = bf2f(sv.y), a2 = bf2f(sv.z), a3 = bf2f(sv.w);

        // software pipeline prologue: addresses 2 pairs ahead, vectors 1 ahead
        int cn0 = colidx[cl(s)], cn1 = colidx[cl(s + 1)];
        ushort4 vn0 = *(const ushort4*)(gs + ((size_t)cn0 << 5) + (l8 << 2));
        ushort4 vn1 = *(const ushort4*)(gs + ((size_t)cn1 << 5) + (l8 << 2));
        cn0 = colidx[cl(s + 2)];
        cn1 = colidx[cl(s + 3)];

        for (int i = s; i < e; i += 2) {
            ushort4 u0 = vn0, u1 = vn1;      // current pair (gathered last iter)
            // issue next pair's gathers (addresses loaded 2 iters ago)
            vn0 = *(const ushort4*)(gs + ((size_t)cn0 << 5) + (l8 << 2));
            vn1 = *(const ushort4*)(gs + ((size_t)cn1 << 5) + (l8 << 2));
            // load addresses two pairs ahead
            cn0 = colidx[cl(i + 4)];
            cn1 = colidx[cl(i + 5)];
            float m1 = (i + 1 < e) ? 1.f : 0.f;
            a0 += bf2f(u0.x); a1 += bf2f(u0.y);
            a2 += bf2f(u0.z); a3 += bf2f(u0.w);
            a0 = fmaf(m1, bf2f(u1.x), a0); a1 = fmaf(m1, bf2f(u1.y), a1);
            a2 = fmaf(m1, bf2f(u1.z), a2); a3 = fmaf(m1, bf2f(u1.w), a3);
        }
        if (valid) {
            float r0 = a0 * rs, r1 = a1 * rs, r2 = a2 * rs, r3 = a3 * rs;
            ushort4 o;
            o.x = f2bf(r0); o.y = f2bf(r1); o.z = f2bf(r2); o.w = f2bf(r3);
            union { ushort4 u4; unsigned long long u64; } cvt;
            cvt.u4 = o;
            __builtin_nontemporal_store(
                cvt.u64, (unsigned long long*)(os + ((size_t)node << 5) + (l8 << 2)));
            sa0 += r0; sa1 += r1; sa2 += r2; sa3 += r3;
            qa0 += r0 * r0; qa1 += r1 * r1; qa2 += r2 * r2; qa3 += r3 * r3;
        }
    }
    // one-time wave reduce across the 8 groups (lanes with equal l8 sum up)
#pragma unroll
    for (int off = 8; off < 64; off <<= 1) {
        sa0 += __shfl_xor(sa0, off); sa1 += __shfl_xor(sa1, off);
        sa2 += __shfl_xor(sa2, off); sa3 += __shfl_xor(sa3, off);
        qa0 += __shfl_xor(qa0, off); qa1 += __shfl_xor(qa1, off);
        qa2 += __shfl_xor(qa2, off); qa3 += __shfl_xor(qa3, off);
    }
    __shared__ float ls[32], lq[32];
    if (threadIdx.x < 32) { ls[threadIdx.x] = 0.f; lq[threadIdx.x] = 0.f; }
    __syncthreads();
    if (lane < 8) {
        atomicAdd(&ls[l8 * 4 + 0], sa0); atomicAdd(&lq[l8 * 4 + 0], qa0);
        atomicAdd(&ls[l8 * 4 + 1], sa1); atomicAdd(&lq[l8 * 4 + 1], qa1);
        atomicAdd(&ls[l8 * 4 + 2], sa2); atomicAdd(&lq[l8 * 4 + 2], qa2);
        atomicAdd(&ls[l8 * 4 + 3], sa3); atomicAdd(&lq[l8 * 4 + 3], qa3);
    }
    __syncthreads();
    if (threadIdx.x < 32) {
        atomicAdd(&stats[slice * 32 + threadIdx.x], ls[threadIdx.x]);
        atomicAdd(&stats[HID + slice * 32 + threadIdx.x], lq[threadIdx.x]);
    }
}

// ---------------------------------------------------------------------------
// BatchNorm apply (+relu, bf16, slice-major), per-block LDS scsh precompute.
// ---------------------------------------------------------------------------
__global__ __launch_bounds__(256) void k_bnapply_bf(const unsigned short* __restrict__ X,
                                                    unsigned short* __restrict__ Y,
                                                    const float* __restrict__ stats,
                                                    const float* __restrict__ gamma,
                                                    const float* __restrict__ beta) {
    __shared__ float s_sc[64], s_sh[64];
    int i = blockIdx.x * 256 + threadIdx.x;  // over 8*N*4 ushort8 groups (exact)
    int slice_lo = (blockIdx.x * 256) / (N_NODES * 4);
    int slice_hi = (blockIdx.x * 256 + 255) / (N_NODES * 4);
    if (threadIdx.x < 64) {
        int half = threadIdx.x >> 5;
        int c = threadIdx.x & 31;
        int sl = half ? slice_hi : slice_lo;
        float sc, sh;
        bn_scsh(stats, gamma, beta, sl * 32 + c, sc, sh);
        s_sc[threadIdx.x] = sc; s_sh[threadIdx.x] = sh;
    }
    __syncthreads();
    int slice = i / (N_NODES * 4);
    int sel = (slice != slice_lo) ? 32 : 0;
    int c8 = sel + (i & 3) * 8;              // N*4 % 4 == 0 -> rem&3 == i&3
    ushort8v v = *(const ushort8v*)(X + (size_t)i * 8);
    ushort8v o;
#pragma unroll
    for (int k = 0; k < 8; ++k) {
        float f = bf2f((unsigned short)v[k]);
        o[k] = f2bf(fmaxf(f * s_sc[c8 + k] + s_sh[c8 + k], 0.f));
    }
    *(ushort8v*)(Y + (size_t)i * 8) = o;
}

// ---------------------------------------------------------------------------
// Head: optional fused BN then logits = v @ W(256x2) + b, log_softmax.
// One wave per row; H slice-major [8][N][32]. LDS scsh precompute.
// ---------------------------------------------------------------------------
__global__ __launch_bounds__(256) void k_head_bf(const unsigned short* __restrict__ H,
                                                 const float* __restrict__ stats,
                                                 const float* __restrict__ gamma,
                                                 const float* __restrict__ beta,
                                                 const float* __restrict__ W,
                                                 const float* __restrict__ b,
                                                 float* __restrict__ outp) {
    __shared__ float h_sc[HID], h_sh[HID];
    if (stats) {
        float sc, sh;
        bn_scsh(stats, gamma, beta, threadIdx.x, sc, sh);
        h_sc[threadIdx.x] = sc; h_sh[threadIdx.x] = sh;
    }
    __syncthreads();
    int wave = (blockIdx.x * 256 + threadIdx.x) >> 6;
    int lane = threadIdx.x & 63;
    if (wave >= N_NODES) return;
    ushort4 h4 = *(const ushort4*)(
        H + ((size_t)(lane >> 3) * N_NODES + wave) * 32 + (lane & 7) * 4);
    float h0 = bf2f(h4.x), h1 = bf2f(h4.y), h2 = bf2f(h4.z), h3 = bf2f(h4.w);
    if (stats) {
        int ch = lane * 4;
        h0 = fmaxf(h0 * h_sc[ch + 0] + h_sh[ch + 0], 0.f);
        h1 = fmaxf(h1 * h_sc[ch + 1] + h_sh[ch + 1], 0.f);
        h2 = fmaxf(h2 * h_sc[ch + 2] + h_sh[ch + 2], 0.f);
        h3 = fmaxf(h3 * h_sc[ch + 3] + h_sh[ch + 3], 0.f);
    }
    const float2* W2 = (const float2*)W;
    float2 w0 = W2[lane * 4 + 0], w1 = W2[lane * 4 + 1];
    float2 w2 = W2[lane * 4 + 2], w3 = W2[lane * 4 + 3];
    float p0 = h0 * w0.x + h1 * w1.x + h2 * w2.x + h3 * w3.x;
    float p1 = h0 * w0.y + h1 * w1.y + h2 * w2.y + h3 * w3.y;
    for (int off = 32; off > 0; off >>= 1) {
        p0 += __shfl_down(p0, off);
        p1 += __shfl_down(p1, off);
    }
    if (lane == 0) {
        float z0 = p0 + b[0], z1 = p1 + b[1];
        float m = fmaxf(z0, z1);
        float lse = m + logf(expf(z0 - m) + expf(z1 - m));
        outp[(size_t)wave * 2 + 0] = z0 - lse;
        outp[(size_t)wave * 2 + 1] = z1 - lse;
    }
}

// ---------------------------------------------------------------------------
extern "C" void kernel_launch(void* const* d_in, const int* in_sizes, int n_in,
                              void* d_out, int out_size, void* d_ws, size_t ws_size,
                              hipStream_t stream) {
    const float* x       = (const float*)d_in[0];      // N x 512
    const int*   ei      = (const int*)d_in[1];        // 2 x E (rows, cols)
    const float* conv_w0 = (const float*)d_in[2];      // 512 x 256
    const float* conv_ws = (const float*)d_in[3];      // 2 x 256 x 256
    const float* bn_g    = (const float*)d_in[5];
    const float* bn_b    = (const float*)d_in[6];
    const float* fcg_w0  = (const float*)d_in[7];      // 256 x 256
    const float* fcg_ws  = (const float*)d_in[8];      // 2 x 512 x 256
    const float* bng_g   = (const float*)d_in[10];
    const float* bng_b   = (const float*)d_in[11];
    const float* fcl_w   = (const float*)d_in[12];     // 3 x 256 x 256
    const float* bnl_g   = (const float*)d_in[14];
    const float* bnl_b   = (const float*)d_in[15];
    const float* outg_w  = (const float*)d_in[16];     // 256 x 2
    const float* outg_b  = (const float*)d_in[17];
    const float* outl_w  = (const float*)d_in[18];     // 3 x 256 x 2
    const float* outl_b  = (const float*)d_in[19];     // 3 x 2
    float* out = (float*)d_out;                        // (4, N, 2)

    const int* rows = ei;
    const int* cols = ei + E_EDGES;

    // workspace carve
    char* ws = (char*)d_ws;
    size_t off = 0;
    auto carve = [&](size_t bytes) -> void* {
        void* p = ws + off;
        off = (off + bytes + 255) & ~(size_t)255;
        return p;
    };
    const size_t ACT = (size_t)N_NODES * HID * 2;  // 25.6 MB bf16 activation
    unsigned short* xbf = (unsigned short*)carve((size_t)N_NODES * 512 * 2);
    unsigned short* tG  = (unsigned short*)carve(ACT);  // GEMM out
    unsigned short* tA  = (unsigned short*)carve(ACT);  // aggregate out
    unsigned short* hbf = (unsigned short*)carve(ACT);  // h_gcn
    unsigned short* g1  = (unsigned short*)carve(ACT);  // hg ping
    unsigned short* g2  = (unsigned short*)carve(ACT);  // hg pong
    unsigned short* wt_conv0 = (unsigned short*)carve(256 * 512 * 2);
    unsigned short* wt_conv1 = (unsigned short*)carve(256 * 256 * 2);  // +conv2 contiguous
    unsigned short* wt_conv2 = (unsigned short*)carve(256 * 256 * 2);
    unsigned short* wt_fcg0  = (unsigned short*)carve(256 * 256 * 2);
    unsigned short* wt_fcgs0 = (unsigned short*)carve(256 * 512 * 2);  // +fcgs1 contiguous
    unsigned short* wt_fcgs1 = (unsigned short*)carve(256 * 512 * 2);
    unsigned short* wt_fcl0  = (unsigned short*)carve(256 * 256 * 2);  // +fcl1/2 contiguous
    unsigned short* wt_fcl1  = (unsigned short*)carve(256 * 256 * 2);
    unsigned short* wt_fcl2  = (unsigned short*)carve(256 * 256 * 2);
    int*   deg    = (int*)carve(2 * 50048 * 4);  // deg + cursor (one memset)
    int*   cursor = deg + 50048;
    int*   rowptr = (int*)carve((size_t)(N_NODES + 1) * 4);
    float* dinv   = (float*)carve((size_t)N_NODES * 4);
    int*   colidx = (int*)carve((size_t)E_EDGES * 4);
    float* stats_all = (float*)carve(9 * 2 * HID * 4);  // 9 layers x (sum,sumsq)
    int*   scanbuf = (int*)carve(512);  // bsum[64] + boff[64]
    int*   bsum = scanbuf;
    int*   boff = scanbuf + 64;
    (void)off; (void)ws_size; (void)in_sizes; (void)n_in; (void)out_size;

    // --- graph prep + stat zeroing ---
    hipMemsetAsync(deg, 0, 2 * 50048 * 4, stream);
    hipMemsetAsync(stats_all, 0, 9 * 2 * HID * 4, stream);
    k_deg<<<E_EDGES / 256, 256, 0, stream>>>(rows, deg);
    k_dinv<<<(N_NODES + 255) / 256, 256, 0, stream>>>(deg, dinv);
    k_scan1<<<SCAN_NCH, 1024, 0, stream>>>(deg, rowptr, bsum);
    k_scan2<<<1, 64, 0, stream>>>(bsum, boff);
    k_scan3<<<SCAN_NCH, 1024, 0, stream>>>(rowptr, boff);
    k_fill<<<E_EDGES / 256, 256, 0, stream>>>(rows, cols, rowptr, cursor, colidx);

    // --- dtype prep (batched transposes: 5 launches) ---
    k_f2bf_slice<<<N_NODES * 64 / 256, 256, 0, stream>>>(x, xbf);
    k_wt<<<(512 * 256 + 255) / 256, 256, 0, stream>>>(conv_w0, wt_conv0, 512, 512 * 256);
    k_wt<<<(2 * 256 * 256 + 255) / 256, 256, 0, stream>>>(conv_ws, wt_conv1, 256, 2 * 256 * 256);
    k_wt<<<(256 * 256 + 255) / 256, 256, 0, stream>>>(fcg_w0, wt_fcg0, 256, 256 * 256);
    k_wt<<<(2 * 512 * 256 + 255) / 256, 256, 0, stream>>>(fcg_ws, wt_fcgs0, 512, 2 * 512 * 256);
    k_wt<<<(3 * 256 * 256 + 255) / 256, 256, 0, stream>>>(fcl_w, wt_fcl0, 256, 3 * 256 * 256);

    dim3 ggrid((N_NODES + 127) / 128, 2);
    auto gemm = [&](const unsigned short* A0, const unsigned short* A1,
                    int K0, int K, const unsigned short* Bt, unsigned short* C,
                    const float* rs, float* st) {
        k_gemm_mfma<<<ggrid, 256, 0, stream>>>(A0, A1, K0, K, Bt, C, rs, st);
    };
    auto bnapply = [&](float* st, const unsigned short* X, unsigned short* Y,
                       const float* gamma, const float* beta) {
        k_bnapply_bf<<<N_NODES * 32 / 256, 256, 0, stream>>>(X, Y, st, gamma, beta);
    };
    auto agg = [&](const unsigned short* in, unsigned short* outb, float* st) {
        k_aggregate_bf<<<8 * AGG_BPS, 256, 0, stream>>>(in, outb, rowptr, colidx,
                                                        dinv, st);
    };
    float* st;

    // --- GCN layer 0 (K=512) ---
    st = stats_all + 0 * 512;
    gemm(xbf, nullptr, 512, 512, wt_conv0, tG, dinv, nullptr);
    agg(tG, tA, st);
    bnapply(st, tA, g1, bn_g + 0, bn_b + 0);        // h1
    // --- GCN layer 1 ---
    st = stats_all + 1 * 512;
    gemm(g1, nullptr, 256, 256, wt_conv1, tG, dinv, nullptr);
    agg(tG, tA, st);
    bnapply(st, tA, g2, bn_g + 256, bn_b + 256);    // h2
    // --- GCN layer 2 ---
    st = stats_all + 2 * 512;
    gemm(g2, nullptr, 256, 256, wt_conv2, tG, dinv, nullptr);
    agg(tG, tA, st);
    bnapply(st, tA, hbf, bn_g + 512, bn_b + 512);   // h_gcn

    // --- global path level 0 ---
    st = stats_all + 3 * 512;
    gemm(hbf, nullptr, 256, 256, wt_fcg0, tG, nullptr, st);
    bnapply(st, tG, g1, bng_g + 0, bng_b + 0);      // hg0
    // local head 0 (BN fused into head)
    st = stats_all + 4 * 512;
    gemm(g1, nullptr, 256, 256, wt_fcl0, tG, nullptr, st);
    k_head_bf<<<N_NODES / 4, 256, 0, stream>>>(tG, st, bnl_g + 0, bnl_b + 0,
                                               outl_w, outl_b,
                                               out + (size_t)1 * N_NODES * 2);
    // --- level 1: xg1 = concat(hg0, h) @ fcg_ws[0]  (dual-A, K=512) ---
    st = stats_all + 5 * 512;
    gemm(g1, hbf, 256, 512, wt_fcgs0, tG, nullptr, st);
    bnapply(st, tG, g2, bng_g + 256, bng_b + 256);  // hg1
    // local head 1 (BN fused into head)
    st = stats_all + 6 * 512;
    gemm(g2, nullptr, 256, 256, wt_fcl1, tG, nullptr, st);
    k_head_bf<<<N_NODES / 4, 256, 0, stream>>>(tG, st, bnl_g + 256, bnl_b + 256,
                                               outl_w + 512, outl_b + 2,
                                               out + (size_t)2 * N_NODES * 2);
    // --- level 2: xg2 = concat(hg1, h) @ fcg_ws[1] ---
    st = stats_all + 7 * 512;
    gemm(g2, hbf, 256, 512, wt_fcgs1, tG, nullptr, st);
    bnapply(st, tG, g1, bng_g + 512, bng_b + 512);  // hg2
    // local head 2 (BN fused into head)
    st = stats_all + 8 * 512;
    gemm(g1, nullptr, 256, 256, wt_fcl2, tG, nullptr, st);
    k_head_bf<<<N_NODES / 4, 256, 0, stream>>>(tG, st, bnl_g + 512, bnl_b + 512,
                                               outl_w + 1024, outl_b + 4,
                                               out + (size_t)3 * N_NODES * 2);
    // global head (og) from hg2 (already BN-applied)
    k_head_bf<<<N_NODES / 4, 256, 0, stream>>>(g1, nullptr, nullptr, nullptr,
                                               outg_w, outg_b, out);
}

// Round 7
// 904.068 us; speedup vs baseline: 1.0305x; 1.0305x over previous
//
#include <hip/hip_runtime.h>
#include <math.h>

#define N_NODES 50000
#define E_EDGES 800000
#define HID 256
#define EPS_BN 1e-5f

// aggregate: blocks per channel-slice (8 slices, slice = blockIdx & 7 -> XCD)
#define AGG_BPS 256

// parallel scan chunking
#define SCAN_CHUNK 1024
#define SCAN_NCH ((N_NODES + SCAN_CHUNK - 1) / SCAN_CHUNK)   // 49

typedef __attribute__((ext_vector_type(8))) short short8;            // bf16x8 MFMA frag
typedef __attribute__((ext_vector_type(4))) float floatx4;           // fp32x4 acc frag
typedef __attribute__((ext_vector_type(8))) unsigned short ushort8v; // bf16x8 mem

// ---------------------------------------------------------------------------
// bf16 helpers (RNE)
// ---------------------------------------------------------------------------
__device__ __forceinline__ unsigned short f2bf(float f) {
    unsigned u = __float_as_uint(f);
    u = (u + 0x7FFFu + ((u >> 16) & 1u)) >> 16;
    return (unsigned short)u;
}
__device__ __forceinline__ float bf2f(unsigned short b) {
    return __uint_as_float(((unsigned)b) << 16);
}
// BN scale/shift from raw stats (sum, sumsq) + gamma/beta
__device__ __forceinline__ void bn_scsh(const float* stats, const float* gamma,
                                        const float* beta, int ch,
                                        float& sc, float& sh) {
    const float invn = 1.0f / (float)N_NODES;
    float mean = stats[ch] * invn;
    float var = stats[HID + ch] * invn - mean * mean;
    var = fmaxf(var, 0.f);
    sc = gamma[ch] * rsqrtf(var + EPS_BN);
    sh = beta[ch] - mean * sc;
}

// ---------------------------------------------------------------------------
// Graph preprocessing
// ---------------------------------------------------------------------------
__global__ __launch_bounds__(256) void k_deg(const int* __restrict__ rows,
                                             int* __restrict__ deg) {
    int e = blockIdx.x * 256 + threadIdx.x;   // E_EDGES % 256 == 0
    atomicAdd(&deg[rows[e]], 1);
}

__global__ __launch_bounds__(256) void k_dinv(const int* __restrict__ deg,
                                              float* __restrict__ dinv) {
    int n = blockIdx.x * 256 + threadIdx.x;
    if (n < N_NODES) dinv[n] = rsqrtf((float)deg[n] + 1.0f);  // +1 self loop
}

// parallel exclusive scan, 3 kernels
__global__ __launch_bounds__(1024) void k_scan1(const int* __restrict__ deg,
                                                int* __restrict__ rowptr,
                                                int* __restrict__ bsum) {
    __shared__ int wsum[16];
    int tid = threadIdx.x, lane = tid & 63, w = tid >> 6;
    int idx = blockIdx.x * SCAN_CHUNK + tid;
    int v = (idx < N_NODES) ? deg[idx] : 0;
    int x = v;
#pragma unroll
    for (int d = 1; d < 64; d <<= 1) {
        int t = __shfl_up(x, d);
        if (lane >= d) x += t;
    }
    if (lane == 63) wsum[w] = x;
    __syncthreads();
    if (w == 0) {
        int ws = (lane < 16) ? wsum[lane] : 0;
#pragma unroll
        for (int d = 1; d < 16; d <<= 1) {
            int t = __shfl_up(ws, d);
            if (lane >= d) ws += t;
        }
        if (lane < 16) wsum[lane] = ws;  // inclusive over waves
    }
    __syncthreads();
    int wbase = (w > 0) ? wsum[w - 1] : 0;
    if (idx < N_NODES) rowptr[idx] = wbase + x - v;   // block-local exclusive
    if (tid == 0) bsum[blockIdx.x] = wsum[15];        // block total
}
__global__ __launch_bounds__(64) void k_scan2(const int* __restrict__ bsum,
                                              int* __restrict__ boff) {
    int lane = threadIdx.x;
    int v = (lane < SCAN_NCH) ? bsum[lane] : 0;
    int x = v;
#pragma unroll
    for (int d = 1; d < 64; d <<= 1) {
        int t = __shfl_up(x, d);
        if (lane >= d) x += t;
    }
    if (lane < SCAN_NCH) boff[lane] = x - v;
    if (lane == SCAN_NCH - 1) boff[SCAN_NCH] = x;     // grand total
}
__global__ __launch_bounds__(1024) void k_scan3(int* __restrict__ rowptr,
                                                const int* __restrict__ boff) {
    int idx = blockIdx.x * SCAN_CHUNK + threadIdx.x;
    if (idx < N_NODES) rowptr[idx] += boff[blockIdx.x];
    if (blockIdx.x == 0 && threadIdx.x == 0) rowptr[N_NODES] = boff[SCAN_NCH];
}

__global__ __launch_bounds__(256) void k_fill(const int* __restrict__ rows,
                                              const int* __restrict__ cols,
                                              const int* __restrict__ rowptr,
                                              int* __restrict__ cursor,
                                              int* __restrict__ colidx) {
    int e = blockIdx.x * 256 + threadIdx.x;
    int r = rows[e];
    int pos = atomicAdd(&cursor[r], 1);
    colidx[rowptr[r] + pos] = cols[e];
}

// ---------------------------------------------------------------------------
// fp32 [N][512] -> bf16 slice-major [16][N][32]
// ---------------------------------------------------------------------------
__global__ __launch_bounds__(256) void k_f2bf_slice(const float* __restrict__ X,
                                                    unsigned short* __restrict__ Y) {
    int i = blockIdx.x * 256 + threadIdx.x;     // over 16*N*4 ushort8 groups, exact
    int slice = i / (N_NODES * 4);              // 0..15
    int rem = i - slice * (N_NODES * 4);
    int node = rem >> 2, p8 = rem & 3;
    const float* xp = X + (size_t)node * 512 + slice * 32 + p8 * 8;
    float4 va = ((const float4*)xp)[0];
    float4 vb = ((const float4*)xp)[1];
    ushort8v o;
    o[0] = f2bf(va.x); o[1] = f2bf(va.y); o[2] = f2bf(va.z); o[3] = f2bf(va.w);
    o[4] = f2bf(vb.x); o[5] = f2bf(vb.y); o[6] = f2bf(vb.z); o[7] = f2bf(vb.w);
    *(ushort8v*)(Y + (size_t)i * 8) = o;
}

// batched W transpose: nmat matrices [K][256] fp32 -> [256][K] bf16 each
__global__ __launch_bounds__(256) void k_wt(const float* __restrict__ W,
                                            unsigned short* __restrict__ Wt,
                                            int K, int total) {
    int idx = blockIdx.x * 256 + threadIdx.x;
    if (idx >= total) return;
    int KS = K << 8;
    int m = idx / KS;
    int rel = idx - m * KS;
    int k = rel >> 8;          // / HID
    int n = rel & 255;         // % HID
    Wt[(size_t)m * KS + (size_t)n * K + k] = f2bf(W[idx]);
}

// ---------------------------------------------------------------------------
// bf16 MFMA GEMM: C(bf16) = rowscale(.)*(A @ Bt^T)
//   ROUND-11: double-buffered k-loop with COUNTED vmcnt (T4 recipe).
//   Round-10 post-mortem: __syncthreads() at the loop tail emits
//   s_waitcnt vmcnt(0) -- draining the stage(c+1) loads just issued, so
//   the double-buffer was structurally defeated (the documented m99/m100
//   null). Fix: inline-asm s_waitcnt vmcnt(4) (the 4 newest loads = chunk
//   c+1 keep flying) + RAW __builtin_amdgcn_s_barrier() (no implicit
//   drain). sched_barrier(0) after the first barrier stops ds_read
//   hoisting (rule 18); explicit lgkmcnt(0) before the tail barrier stops
//   in-flight ds_reads crossing into the buffer-overwrite window.
//   Buffer-reuse proof: iter c reads buf c&1; iter c+1 stages into
//   (c+2)&1 == c&1, separated by the tail barrier.
//   LDS 36 KB (4x8KB staging union'd with 34.8KB epilogue tile + 1KB
//   stats) -> 4 blocks/CU. A slice-major [K/32][N][32]; Bt [256][K];
//   C slice-major [8][N][32]; epilogue through LDS (pad-136, 16B stores).
// ---------------------------------------------------------------------------
__global__ __launch_bounds__(256) void k_gemm_mfma(
    const unsigned short* __restrict__ A0,
    const unsigned short* __restrict__ A1, int K0, int K,
    const unsigned short* __restrict__ Bt,
    unsigned short* __restrict__ C,
    const float* __restrict__ rowscale,
    float* __restrict__ stats)
{
    __shared__ alignas(16) unsigned char smem[36864];
    // staging: A buffers at ushort-offset 0 / 4096, B at 8192 / 12288
    unsigned short* sbase = (unsigned short*)smem;
    int tid = threadIdx.x;
    int wid = tid >> 6, lane = tid & 63;
    int row0 = blockIdx.x * 128;
    int n0 = blockIdx.y * 128;
    int wrow = (wid & 1) * 64, wcol = (wid >> 1) * 64;
    int lr = lane >> 2;            // staging: row within 16-row group
    int lk = (lane & 3) * 8;       // staging: element offset in k
    int qq = lane >> 4, mr = lane & 15;

    floatx4 acc[4][4];
#pragma unroll
    for (int i = 0; i < 4; ++i)
#pragma unroll
        for (int j = 0; j < 4; ++j) {
            floatx4 z = {0.f, 0.f, 0.f, 0.f};
            acc[i][j] = z;
        }

    int KL = K >> 5;   // number of 32-K chunks (K0 % 32 == 0 guaranteed)

    auto stage = [&](int c, int b) {   // exactly 4 global_load_lds per wave
        int kk = c << 5;
        const unsigned short* Abase =
            (kk < K0) ? A0 + (size_t)(kk >> 5) * (N_NODES * 32)
                      : A1 + (size_t)((kk - K0) >> 5) * (N_NODES * 32);
        unsigned short* Adst = sbase + b * 4096;
        unsigned short* Bdst = sbase + 8192 + b * 4096;
#pragma unroll
        for (int i = 0; i < 2; ++i) {
            int rloc = wid * 32 + i * 16 + lr;
            int grow = row0 + rloc;
            if (grow > N_NODES - 1) grow = N_NODES - 1;  // clamp (stores guarded)
            const unsigned short* gp = Abase + (size_t)grow * 32 + lk;
            unsigned short* l = Adst + (wid * 32 + i * 16) * 32;
            __builtin_amdgcn_global_load_lds(
                (const __attribute__((address_space(1))) void*)gp,
                (__attribute__((address_space(3))) void*)l, 16, 0, 0);
        }
#pragma unroll
        for (int i = 0; i < 2; ++i) {
            int nloc = wid * 32 + i * 16 + lr;
            const unsigned short* gp = Bt + (size_t)(n0 + nloc) * K + kk + lk;
            unsigned short* l = Bdst + (wid * 32 + i * 16) * 32;
            __builtin_amdgcn_global_load_lds(
                (const __attribute__((address_space(1))) void*)gp,
                (__attribute__((address_space(3))) void*)l, 16, 0, 0);
        }
    };

    stage(0, 0);
    for (int c = 0; c < KL; ++c) {
        int cur = c & 1;
        if (c + 1 < KL) {
            stage(c + 1, cur ^ 1);   // issue next chunk; its 4 loads keep flying
            asm volatile("s_waitcnt vmcnt(4)" ::: "memory");
        } else {
            asm volatile("s_waitcnt vmcnt(0)" ::: "memory");
        }
        __builtin_amdgcn_s_barrier();          // raw: no implicit drain
        __builtin_amdgcn_sched_barrier(0);     // pin: no ds_read hoisting
        const unsigned short* Asrc = sbase + cur * 4096;
        const unsigned short* Bsrc = sbase + 8192 + cur * 4096;
        short8 af[4], bfv[4];
#pragma unroll
        for (int i = 0; i < 4; ++i)
            af[i] = *(const short8*)(Asrc + (wrow + i * 16 + mr) * 32 + qq * 8);
#pragma unroll
        for (int j = 0; j < 4; ++j)
            bfv[j] = *(const short8*)(Bsrc + (wcol + j * 16 + mr) * 32 + qq * 8);
#pragma unroll
        for (int i = 0; i < 4; ++i)
#pragma unroll
            for (int j = 0; j < 4; ++j)
                acc[i][j] = __builtin_amdgcn_mfma_f32_16x16x32_bf16(
                    af[i], bfv[j], acc[i][j], 0, 0, 0);
        asm volatile("s_waitcnt lgkmcnt(0)" ::: "memory");  // ds_reads complete
        __builtin_amdgcn_s_barrier();          // now buf cur may be overwritten
    }
    __syncthreads();   // full drain before LDS reuse by epilogue

    // ---- epilogue through LDS ----
    unsigned short* lds_c = (unsigned short*)smem;        // [128][136] ushort
    float* ls = (float*)(smem + 34816);                   // [128] col sums
    float* lq = ls + 128;                                 // [128] col sumsq
    if (stats) ((float*)(smem + 34816))[tid] = 0.f;       // zero ls+lq

    float psum[4] = {0.f, 0.f, 0.f, 0.f};
    float psq[4]  = {0.f, 0.f, 0.f, 0.f};
#pragma unroll
    for (int i = 0; i < 4; ++i) {
        int trow_base = wrow + i * 16 + qq * 4;
#pragma unroll
        for (int r = 0; r < 4; ++r) {
            int trow = trow_base + r;
            int grow = row0 + trow;
            bool rok = grow < N_NODES;
            float rs = 1.0f;
            if (rowscale && rok) rs = rowscale[grow];
#pragma unroll
            for (int j = 0; j < 4; ++j) {
                float v = acc[i][j][r] * rs;
                lds_c[trow * 136 + wcol + j * 16 + mr] = f2bf(v);
                if (rok) { psum[j] += v; psq[j] += v * v; }
            }
        }
    }
    __syncthreads();
    if (stats) {
#pragma unroll
        for (int j = 0; j < 4; ++j) {
            int lc = wcol + j * 16 + mr;
            atomicAdd(&ls[lc], psum[j]);
            atomicAdd(&lq[lc], psq[j]);
        }
    }
    // coalesced slice-major stores: 8 x 16B per thread
    int rowlim = N_NODES - row0; if (rowlim > 128) rowlim = 128;
    int sbase_n = n0 >> 5;
#pragma unroll
    for (int u = 0; u < 8; ++u) {
        int uid = tid + 256 * u;            // 0..2047
        int row = uid >> 4;
        int q = (uid >> 2) & 3;
        int sub = uid & 3;
        if (row < rowlim) {
            ushort8v vv = *(const ushort8v*)(lds_c + row * 136 + q * 32 + sub * 8);
            *(ushort8v*)(C + ((size_t)(sbase_n + q) * N_NODES + row0 + row) * 32 + sub * 8) = vv;
        }
    }
    if (stats) {
        __syncthreads();
        if (tid < 128) atomicAdd(&stats[n0 + tid], ls[tid]);
        else atomicAdd(&stats[HID + n0 + (tid - 128)], lq[tid - 128]);
    }
}

// ---------------------------------------------------------------------------
// GCN aggregation (round-7 version, known-good 64.5 us / 32.2 MB FETCH):
// channel-sliced (slice = blockIdx&7 -> XCD; [N][32] bf16 = 3.2 MB < 4 MB
// per-XCD L2) + group-per-node (8-lane group owns a node, ushort4/lane)
// + 2-stage software pipeline.
// ---------------------------------------------------------------------------
__global__ __launch_bounds__(256) void k_aggregate_bf(
    const unsigned short* __restrict__ g,   // [8][N][32] bf16
    unsigned short* __restrict__ outp,      // [8][N][32] bf16
    const int* __restrict__ rowptr,
    const int* __restrict__ colidx,
    const float* __restrict__ dinv,
    float* __restrict__ stats) {
    int lane = threadIdx.x & 63;
    int wid = threadIdx.x >> 6;
    int slice = blockIdx.x & 7;
    int bslice = blockIdx.x >> 3;
    const unsigned short* gs = g + (size_t)slice * (N_NODES * 32);
    unsigned short* os = outp + (size_t)slice * (N_NODES * 32);
    int g8 = lane >> 3;   // group 0..7 (owns one node per round)
    int l8 = lane & 7;    // lane within group: channels l8*4 .. l8*4+3
    int wavebase = (bslice * 4 + wid) * 8;
    const int stride = AGG_BPS * 4 * 8;   // nodes per round (8192)

    float sa0 = 0.f, sa1 = 0.f, sa2 = 0.f, sa3 = 0.f;  // per-lane stats acc
    float qa0 = 0.f, qa1 = 0.f, qa2 = 0.f, qa3 = 0.f;

    for (int nb = wavebase; nb < N_NODES; nb += stride) {
        int node = nb + g8;
        bool valid = node < N_NODES;
        int nc = valid ? node : N_NODES - 1;
        int s = rowptr[nc];
        int e = valid ? rowptr[nc + 1] : s;
        int e1 = e - 1;
        // index clamp: keeps prefetch loads in-bounds for any j >= s
        auto cl = [&](int j) { int t = j < e1 ? j : e1; return t > 0 ? t : 0; };

        // init accumulators with the self contribution (overlaps edge loop)
        ushort4 sv = *(const ushort4*)(gs + ((size_t)nc << 5) + (l8 << 2));
        float rs = dinv[nc];
        float a0 = bf2f(sv.x), a1 = bf2f(sv.y), a2 = bf2f(sv.z), a3 = bf2f(sv.w);

        // software pipeline prologue: addresses 2 pairs ahead, vectors 1 ahead
        int cn0 = colidx[cl(s)], cn1 = colidx[cl(s + 1)];
        ushort4 vn0 = *(const ushort4*)(gs + ((size_t)cn0 << 5) + (l8 << 2));
        ushort4 vn1 = *(const ushort4*)(gs + ((size_t)cn1 << 5) + (l8 << 2));
        cn0 = colidx[cl(s + 2)];
        cn1 = colidx[cl(s + 3)];

        for (int i = s; i < e; i += 2) {
            ushort4 u0 = vn0, u1 = vn1;      // current pair (gathered last iter)
            // issue next pair's gathers (addresses loaded 2 iters ago)
            vn0 = *(const ushort4*)(gs + ((size_t)cn0 << 5) + (l8 << 2));
            vn1 = *(const ushort4*)(gs + ((size_t)cn1 << 5) + (l8 << 2));
            // load addresses two pairs ahead
            cn0 = colidx[cl(i + 4)];
            cn1 = colidx[cl(i + 5)];
            float m1 = (i + 1 < e) ? 1.f : 0.f;
            a0 += bf2f(u0.x); a1 += bf2f(u0.y);
            a2 += bf2f(u0.z); a3 += bf2f(u0.w);
            a0 = fmaf(m1, bf2f(u1.x), a0); a1 = fmaf(m1, bf2f(u1.y), a1);
            a2 = fmaf(m1, bf2f(u1.z), a2); a3 = fmaf(m1, bf2f(u1.w), a3);
        }
        if (valid) {
            float r0 = a0 * rs, r1 = a1 * rs, r2 = a2 * rs, r3 = a3 * rs;
            ushort4 o;
            o.x = f2bf(r0); o.y = f2bf(r1); o.z = f2bf(r2); o.w = f2bf(r3);
            union { ushort4 u4; unsigned long long u64; } cvt;
            cvt.u4 = o;
            __builtin_nontemporal_store(
                cvt.u64, (unsigned long long*)(os + ((size_t)node << 5) + (l8 << 2)));
            sa0 += r0; sa1 += r1; sa2 += r2; sa3 += r3;
            qa0 += r0 * r0; qa1 += r1 * r1; qa2 += r2 * r2; qa3 += r3 * r3;
        }
    }
    // one-time wave reduce across the 8 groups (lanes with equal l8 sum up)
#pragma unroll
    for (int off = 8; off < 64; off <<= 1) {
        sa0 += __shfl_xor(sa0, off); sa1 += __shfl_xor(sa1, off);
        sa2 += __shfl_xor(sa2, off); sa3 += __shfl_xor(sa3, off);
        qa0 += __shfl_xor(qa0, off); qa1 += __shfl_xor(qa1, off);
        qa2 += __shfl_xor(qa2, off); qa3 += __shfl_xor(qa3, off);
    }
    __shared__ float ls[32], lq[32];
    if (threadIdx.x < 32) { ls[threadIdx.x] = 0.f; lq[threadIdx.x] = 0.f; }
    __syncthreads();
    if (lane < 8) {
        atomicAdd(&ls[l8 * 4 + 0], sa0); atomicAdd(&lq[l8 * 4 + 0], qa0);
        atomicAdd(&ls[l8 * 4 + 1], sa1); atomicAdd(&lq[l8 * 4 + 1], qa1);
        atomicAdd(&ls[l8 * 4 + 2], sa2); atomicAdd(&lq[l8 * 4 + 2], qa2);
        atomicAdd(&ls[l8 * 4 + 3], sa3); atomicAdd(&lq[l8 * 4 + 3], qa3);
    }
    __syncthreads();
    if (threadIdx.x < 32) {
        atomicAdd(&stats[slice * 32 + threadIdx.x], ls[threadIdx.x]);
        atomicAdd(&stats[HID + slice * 32 + threadIdx.x], lq[threadIdx.x]);
    }
}

// ---------------------------------------------------------------------------
// BatchNorm apply (+relu, bf16, slice-major), per-block LDS scsh precompute.
// ---------------------------------------------------------------------------
__global__ __launch_bounds__(256) void k_bnapply_bf(const unsigned short* __restrict__ X,
                                                    unsigned short* __restrict__ Y,
                                                    const float* __restrict__ stats,
                                                    const float* __restrict__ gamma,
                                                    const float* __restrict__ beta) {
    __shared__ float s_sc[64], s_sh[64];
    int i = blockIdx.x * 256 + threadIdx.x;  // over 8*N*4 ushort8 groups (exact)
    int slice_lo = (blockIdx.x * 256) / (N_NODES * 4);
    int slice_hi = (blockIdx.x * 256 + 255) / (N_NODES * 4);
    if (threadIdx.x < 64) {
        int half = threadIdx.x >> 5;
        int c = threadIdx.x & 31;
        int sl = half ? slice_hi : slice_lo;
        float sc, sh;
        bn_scsh(stats, gamma, beta, sl * 32 + c, sc, sh);
        s_sc[threadIdx.x] = sc; s_sh[threadIdx.x] = sh;
    }
    __syncthreads();
    int slice = i / (N_NODES * 4);
    int sel = (slice != slice_lo) ? 32 : 0;
    int c8 = sel + (i & 3) * 8;              // N*4 % 4 == 0 -> rem&3 == i&3
    ushort8v v = *(const ushort8v*)(X + (size_t)i * 8);
    ushort8v o;
#pragma unroll
    for (int k = 0; k < 8; ++k) {
        float f = bf2f((unsigned short)v[k]);
        o[k] = f2bf(fmaxf(f * s_sc[c8 + k] + s_sh[c8 + k], 0.f));
    }
    *(ushort8v*)(Y + (size_t)i * 8) = o;
}

// ---------------------------------------------------------------------------
// Head: optional fused BN then logits = v @ W(256x2) + b, log_softmax.
// One wave per row; H slice-major [8][N][32]. LDS scsh precompute.
// ---------------------------------------------------------------------------
__global__ __launch_bounds__(256) void k_head_bf(const unsigned short* __restrict__ H,
                                                 const float* __restrict__ stats,
                                                 const float* __restrict__ gamma,
                                                 const float* __restrict__ beta,
                                                 const float* __restrict__ W,
                                                 const float* __restrict__ b,
                                                 float* __restrict__ outp) {
    __shared__ float h_sc[HID], h_sh[HID];
    if (stats) {
        float sc, sh;
        bn_scsh(stats, gamma, beta, threadIdx.x, sc, sh);
        h_sc[threadIdx.x] = sc; h_sh[threadIdx.x] = sh;
    }
    __syncthreads();
    int wave = (blockIdx.x * 256 + threadIdx.x) >> 6;
    int lane = threadIdx.x & 63;
    if (wave >= N_NODES) return;
    ushort4 h4 = *(const ushort4*)(
        H + ((size_t)(lane >> 3) * N_NODES + wave) * 32 + (lane & 7) * 4);
    float h0 = bf2f(h4.x), h1 = bf2f(h4.y), h2 = bf2f(h4.z), h3 = bf2f(h4.w);
    if (stats) {
        int ch = lane * 4;
        h0 = fmaxf(h0 * h_sc[ch + 0] + h_sh[ch + 0], 0.f);
        h1 = fmaxf(h1 * h_sc[ch + 1] + h_sh[ch + 1], 0.f);
        h2 = fmaxf(h2 * h_sc[ch + 2] + h_sh[ch + 2], 0.f);
        h3 = fmaxf(h3 * h_sc[ch + 3] + h_sh[ch + 3], 0.f);
    }
    const float2* W2 = (const float2*)W;
    float2 w0 = W2[lane * 4 + 0], w1 = W2[lane * 4 + 1];
    float2 w2 = W2[lane * 4 + 2], w3 = W2[lane * 4 + 3];
    float p0 = h0 * w0.x + h1 * w1.x + h2 * w2.x + h3 * w3.x;
    float p1 = h0 * w0.y + h1 * w1.y + h2 * w2.y + h3 * w3.y;
    for (int off = 32; off > 0; off >>= 1) {
        p0 += __shfl_down(p0, off);
        p1 += __shfl_down(p1, off);
    }
    if (lane == 0) {
        float z0 = p0 + b[0], z1 = p1 + b[1];
        float m = fmaxf(z0, z1);
        float lse = m + logf(expf(z0 - m) + expf(z1 - m));
        outp[(size_t)wave * 2 + 0] = z0 - lse;
        outp[(size_t)wave * 2 + 1] = z1 - lse;
    }
}

// ---------------------------------------------------------------------------
extern "C" void kernel_launch(void* const* d_in, const int* in_sizes, int n_in,
                              void* d_out, int out_size, void* d_ws, size_t ws_size,
                              hipStream_t stream) {
    const float* x       = (const float*)d_in[0];      // N x 512
    const int*   ei      = (const int*)d_in[1];        // 2 x E (rows, cols)
    const float* conv_w0 = (const float*)d_in[2];      // 512 x 256
    const float* conv_ws = (const float*)d_in[3];      // 2 x 256 x 256
    const float* bn_g    = (const float*)d_in[5];
    const float* bn_b    = (const float*)d_in[6];
    const float* fcg_w0  = (const float*)d_in[7];      // 256 x 256
    const float* fcg_ws  = (const float*)d_in[8];      // 2 x 512 x 256
    const float* bng_g   = (const float*)d_in[10];
    const float* bng_b   = (const float*)d_in[11];
    const float* fcl_w   = (const float*)d_in[12];     // 3 x 256 x 256
    const float* bnl_g   = (const float*)d_in[14];
    const float* bnl_b   = (const float*)d_in[15];
    const float* outg_w  = (const float*)d_in[16];     // 256 x 2
    const float* outg_b  = (const float*)d_in[17];
    const float* outl_w  = (const float*)d_in[18];     // 3 x 256 x 2
    const float* outl_b  = (const float*)d_in[19];     // 3 x 2
    float* out = (float*)d_out;                        // (4, N, 2)

    const int* rows = ei;
    const int* cols = ei + E_EDGES;

    // workspace carve
    char* ws = (char*)d_ws;
    size_t off = 0;
    auto carve = [&](size_t bytes) -> void* {
        void* p = ws + off;
        off = (off + bytes + 255) & ~(size_t)255;
        return p;
    };
    const size_t ACT = (size_t)N_NODES * HID * 2;  // 25.6 MB bf16 activation
    unsigned short* xbf = (unsigned short*)carve((size_t)N_NODES * 512 * 2);
    unsigned short* tG  = (unsigned short*)carve(ACT);  // GEMM out
    unsigned short* tA  = (unsigned short*)carve(ACT);  // aggregate out
    unsigned short* hbf = (unsigned short*)carve(ACT);  // h_gcn
    unsigned short* g1  = (unsigned short*)carve(ACT);  // hg ping
    unsigned short* g2  = (unsigned short*)carve(ACT);  // hg pong
    unsigned short* wt_conv0 = (unsigned short*)carve(256 * 512 * 2);
    unsigned short* wt_conv1 = (unsigned short*)carve(256 * 256 * 2);  // +conv2 contiguous
    unsigned short* wt_conv2 = (unsigned short*)carve(256 * 256 * 2);
    unsigned short* wt_fcg0  = (unsigned short*)carve(256 * 256 * 2);
    unsigned short* wt_fcgs0 = (unsigned short*)carve(256 * 512 * 2);  // +fcgs1 contiguous
    unsigned short* wt_fcgs1 = (unsigned short*)carve(256 * 512 * 2);
    unsigned short* wt_fcl0  = (unsigned short*)carve(256 * 256 * 2);  // +fcl1/2 contiguous
    unsigned short* wt_fcl1  = (unsigned short*)carve(256 * 256 * 2);
    unsigned short* wt_fcl2  = (unsigned short*)carve(256 * 256 * 2);
    int*   deg    = (int*)carve(2 * 50048 * 4);  // deg + cursor (one memset)
    int*   cursor = deg + 50048;
    int*   rowptr = (int*)carve((size_t)(N_NODES + 1) * 4);
    float* dinv   = (float*)carve((size_t)N_NODES * 4);
    int*   colidx = (int*)carve((size_t)E_EDGES * 4);
    float* stats_all = (float*)carve(9 * 2 * HID * 4);  // 9 layers x (sum,sumsq)
    int*   scanbuf = (int*)carve(512);  // bsum[64] + boff[64]
    int*   bsum = scanbuf;
    int*   boff = scanbuf + 64;
    (void)off; (void)ws_size; (void)in_sizes; (void)n_in; (void)out_size;

    // --- graph prep + stat zeroing ---
    hipMemsetAsync(deg, 0, 2 * 50048 * 4, stream);
    hipMemsetAsync(stats_all, 0, 9 * 2 * HID * 4, stream);
    k_deg<<<E_EDGES / 256, 256, 0, stream>>>(rows, deg);
    k_dinv<<<(N_NODES + 255) / 256, 256, 0, stream>>>(deg, dinv);
    k_scan1<<<SCAN_NCH, 1024, 0, stream>>>(deg, rowptr, bsum);
    k_scan2<<<1, 64, 0, stream>>>(bsum, boff);
    k_scan3<<<SCAN_NCH, 1024, 0, stream>>>(rowptr, boff);
    k_fill<<<E_EDGES / 256, 256, 0, stream>>>(rows, cols, rowptr, cursor, colidx);

    // --- dtype prep (batched transposes: 5 launches) ---
    k_f2bf_slice<<<N_NODES * 64 / 256, 256, 0, stream>>>(x, xbf);
    k_wt<<<(512 * 256 + 255) / 256, 256, 0, stream>>>(conv_w0, wt_conv0, 512, 512 * 256);
    k_wt<<<(2 * 256 * 256 + 255) / 256, 256, 0, stream>>>(conv_ws, wt_conv1, 256, 2 * 256 * 256);
    k_wt<<<(256 * 256 + 255) / 256, 256, 0, stream>>>(fcg_w0, wt_fcg0, 256, 256 * 256);
    k_wt<<<(2 * 512 * 256 + 255) / 256, 256, 0, stream>>>(fcg_ws, wt_fcgs0, 512, 2 * 512 * 256);
    k_wt<<<(3 * 256 * 256 + 255) / 256, 256, 0, stream>>>(fcl_w, wt_fcl0, 256, 3 * 256 * 256);

    dim3 ggrid((N_NODES + 127) / 128, 2);
    auto gemm = [&](const unsigned short* A0, const unsigned short* A1,
                    int K0, int K, const unsigned short* Bt, unsigned short* C,
                    const float* rs, float* st) {
        k_gemm_mfma<<<ggrid, 256, 0, stream>>>(A0, A1, K0, K, Bt, C, rs, st);
    };
    auto bnapply = [&](float* st, const unsigned short* X, unsigned short* Y,
                       const float* gamma, const float* beta) {
        k_bnapply_bf<<<N_NODES * 32 / 256, 256, 0, stream>>>(X, Y, st, gamma, beta);
    };
    auto agg = [&](const unsigned short* in, unsigned short* outb, float* st) {
        k_aggregate_bf<<<8 * AGG_BPS, 256, 0, stream>>>(in, outb, rowptr, colidx,
                                                        dinv, st);
    };
    float* st;

    // --- GCN layer 0 (K=512) ---
    st = stats_all + 0 * 512;
    gemm(xbf, nullptr, 512, 512, wt_conv0, tG, dinv, nullptr);
    agg(tG, tA, st);
    bnapply(st, tA, g1, bn_g + 0, bn_b + 0);        // h1
    // --- GCN layer 1 ---
    st = stats_all + 1 * 512;
    gemm(g1, nullptr, 256, 256, wt_conv1, tG, dinv, nullptr);
    agg(tG, tA, st);
    bnapply(st, tA, g2, bn_g + 256, bn_b + 256);    // h2
    // --- GCN layer 2 ---
    st = stats_all + 2 * 512;
    gemm(g2, nullptr, 256, 256, wt_conv2, tG, dinv, nullptr);
    agg(tG, tA, st);
    bnapply(st, tA, hbf, bn_g + 512, bn_b + 512);   // h_gcn

    // --- global path level 0 ---
    st = stats_all + 3 * 512;
    gemm(hbf, nullptr, 256, 256, wt_fcg0, tG, nullptr, st);
    bnapply(st, tG, g1, bng_g + 0, bng_b + 0);      // hg0
    // local head 0 (BN fused into head)
    st = stats_all + 4 * 512;
    gemm(g1, nullptr, 256, 256, wt_fcl0, tG, nullptr, st);
    k_head_bf<<<N_NODES / 4, 256, 0, stream>>>(tG, st, bnl_g + 0, bnl_b + 0,
                                               outl_w, outl_b,
                                               out + (size_t)1 * N_NODES * 2);
    // --- level 1: xg1 = concat(hg0, h) @ fcg_ws[0]  (dual-A, K=512) ---
    st = stats_all + 5 * 512;
    gemm(g1, hbf, 256, 512, wt_fcgs0, tG, nullptr, st);
    bnapply(st, tG, g2, bng_g + 256, bng_b + 256);  // hg1
    // local head 1 (BN fused into head)
    st = stats_all + 6 * 512;
    gemm(g2, nullptr, 256, 256, wt_fcl1, tG, nullptr, st);
    k_head_bf<<<N_NODES / 4, 256, 0, stream>>>(tG, st, bnl_g + 256, bnl_b + 256,
                                               outl_w + 512, outl_b + 2,
                                               out + (size_t)2 * N_NODES * 2);
    // --- level 2: xg2 = concat(hg1, h) @ fcg_ws[1] ---
    st = stats_all + 7 * 512;
    gemm(g2, hbf, 256, 512, wt_fcgs1, tG, nullptr, st);
    bnapply(st, tG, g1, bng_g + 512, bng_b + 512);  // hg2
    // local head 2 (BN fused into head)
    st = stats_all + 8 * 512;
    gemm(g1, nullptr, 256, 256, wt_fcl2, tG, nullptr, st);
    k_head_bf<<<N_NODES / 4, 256, 0, stream>>>(tG, st, bnl_g + 512, bnl_b + 512,
                                               outl_w + 1024, outl_b + 4,
                                               out + (size_t)3 * N_NODES * 2);
    // global head (og) from hg2 (already BN-applied)
    k_head_bf<<<N_NODES / 4, 256, 0, stream>>>(g1, nullptr, nullptr, nullptr,
                                               outg_w, outg_b, out);
}